// Round 1
// baseline (1270.738 us; speedup 1.0000x reference)
//
#include <hip/hip_runtime.h>
#include <hip/hip_bf16.h>
#include <math.h>
#include <stdint.h>

#define D_MODEL 2048
#define D_FF    8192
#define MTOK    16384   // 4 * 4096 tokens
#define NW      (D_FF * D_MODEL)   // elements per weight matrix

typedef int    i32x4  __attribute__((ext_vector_type(4)));
typedef __bf16 bf16x8 __attribute__((ext_vector_type(8)));

// width-16 async global->LDS (per-lane global addr, wave-uniform LDS base + lane*16)
#define GLOAD_LDS16(gp, lp)                                                   \
  __builtin_amdgcn_global_load_lds(                                           \
      (__attribute__((address_space(1))) void*)(gp),                          \
      (__attribute__((address_space(3))) void*)(lp), 16, 0, 0)

// ---------------- stage 1: deterministic double partial sums of |w| ----------------
__global__ void absum_s1(const float* __restrict__ w1, const float* __restrict__ w2,
                         double* __restrict__ partials) {
    const float* w = blockIdx.y ? w2 : w1;
    __shared__ double sm[256];
    int tid = blockIdx.x * 256 + threadIdx.x;
    double s = 0.0;
    for (int i = tid; i < NW / 4; i += 1024 * 256) {
        float4 v = ((const float4*)w)[i];
        s += (double)fabsf(v.x) + (double)fabsf(v.y) + (double)fabsf(v.z) + (double)fabsf(v.w);
    }
    sm[threadIdx.x] = s;
    __syncthreads();
    for (int off = 128; off > 0; off >>= 1) {
        if (threadIdx.x < off) sm[threadIdx.x] += sm[threadIdx.x + off];
        __syncthreads();
    }
    if (threadIdx.x == 0) partials[blockIdx.y * 1024 + blockIdx.x] = sm[0];
}

// ---------------- stage 2: 1024 partials -> float threshold 0.7*mean ----------------
__global__ void absum_s2(const double* __restrict__ partials, float* __restrict__ thr) {
    __shared__ double sm[256];
    for (int wsel = 0; wsel < 2; ++wsel) {
        const double* p = partials + wsel * 1024;
        double s = p[threadIdx.x] + p[threadIdx.x + 256] + p[threadIdx.x + 512] + p[threadIdx.x + 768];
        sm[threadIdx.x] = s;
        __syncthreads();
        for (int off = 128; off > 0; off >>= 1) {
            if (threadIdx.x < off) sm[threadIdx.x] += sm[threadIdx.x + off];
            __syncthreads();
        }
        if (threadIdx.x == 0) thr[wsel] = (float)(0.7 * (sm[0] / (double)NW));
        __syncthreads();
    }
}

// ---------------- w1 -> ternary i8, elementwise ----------------
__global__ void quantw1(const float* __restrict__ w, const float* __restrict__ thr,
                        int8_t* __restrict__ q) {
    float t = thr[0];
    int i = (blockIdx.x * 256 + threadIdx.x) * 4;
    float4 v = *(const float4*)(w + i);
    char4 o;
    o.x = (fabsf(v.x) >= t) ? (v.x > 0.f ? 1 : -1) : 0;
    o.y = (fabsf(v.y) >= t) ? (v.y > 0.f ? 1 : -1) : 0;
    o.z = (fabsf(v.z) >= t) ? (v.z > 0.f ? 1 : -1) : 0;
    o.w = (fabsf(v.w) >= t) ? (v.w > 0.f ? 1 : -1) : 0;
    *(char4*)(q + i) = o;
}

// ---------------- w2 -> ternary i8, one block per row, + row sums (colsum) ---------
__global__ void quantw2(const float* __restrict__ w, const float* __restrict__ thr,
                        int8_t* __restrict__ q, float* __restrict__ colsum) {
    __shared__ int sm[256];
    float t = thr[1];
    const int row = blockIdx.x;
    const int tid = threadIdx.x;
    int isum = 0;
    #pragma unroll
    for (int j = 0; j < 8; ++j) {
        int idx = row * D_FF + j * 1024 + tid * 4;
        float4 v = *(const float4*)(w + idx);
        char4 o;
        o.x = (fabsf(v.x) >= t) ? (v.x > 0.f ? 1 : -1) : 0;
        o.y = (fabsf(v.y) >= t) ? (v.y > 0.f ? 1 : -1) : 0;
        o.z = (fabsf(v.z) >= t) ? (v.z > 0.f ? 1 : -1) : 0;
        o.w = (fabsf(v.w) >= t) ? (v.w > 0.f ? 1 : -1) : 0;
        isum += o.x + o.y + o.z + o.w;
        *(char4*)(q + idx) = o;
    }
    sm[tid] = isum;
    __syncthreads();
    for (int off = 128; off > 0; off >>= 1) {
        if (tid < off) sm[tid] += sm[tid + off];
        __syncthreads();
    }
    if (tid == 0) colsum[row] = (float)sm[0];
}

// ---------------- x -> per-row symmetric i8, one block per token row ----------------
__global__ void xquant(const float* __restrict__ x, int8_t* __restrict__ xq,
                       float* __restrict__ sx) {
    __shared__ float sm[256];
    const int row = blockIdx.x;
    const int tid = threadIdx.x;
    float4 v[2];
    float mx = 0.f;
    #pragma unroll
    for (int j = 0; j < 2; ++j) {
        v[j] = *(const float4*)(x + (size_t)row * D_MODEL + j * 1024 + tid * 4);
        mx = fmaxf(mx, fmaxf(fmaxf(fabsf(v[j].x), fabsf(v[j].y)),
                             fmaxf(fabsf(v[j].z), fabsf(v[j].w))));
    }
    sm[tid] = mx;
    __syncthreads();
    for (int off = 128; off > 0; off >>= 1) {
        if (tid < off) sm[tid] = fmaxf(sm[tid], sm[tid + off]);
        __syncthreads();
    }
    float m = sm[0];
    float inv = (m > 0.f) ? 127.f / m : 0.f;
    if (tid == 0) sx[row] = (m > 0.f) ? m / 127.f : 0.f;
    #pragma unroll
    for (int j = 0; j < 2; ++j) {
        char4 o;
        o.x = (int8_t)min(127, max(-127, __float2int_rn(v[j].x * inv)));
        o.y = (int8_t)min(127, max(-127, __float2int_rn(v[j].y * inv)));
        o.z = (int8_t)min(127, max(-127, __float2int_rn(v[j].z * inv)));
        o.w = (int8_t)min(127, max(-127, __float2int_rn(v[j].w * inv)));
        *(char4*)(xq + (size_t)row * D_MODEL + j * 1024 + tid * 4) = o;
    }
}

// ---------------- gelu(h) bf16 -> per-row ASYMMETRIC i8 (zero-point via colsum) -----
// g ~= s*qs + o with o = 127*s + gmin, gmin = -0.17 (gelu lower bound).
__global__ void hquant(const __bf16* __restrict__ h, int8_t* __restrict__ hq,
                       float2* __restrict__ sh) {
    __shared__ float sm[256];
    const int row = blockIdx.x;
    const int tid = threadIdx.x;
    const float gmin = -0.17f;
    float vals[4][8];
    float mx = -1e30f;
    #pragma unroll
    for (int j = 0; j < 4; ++j) {
        bf16x8 b = *(const bf16x8*)(h + (size_t)row * D_FF + j * 2048 + tid * 8);
        #pragma unroll
        for (int e = 0; e < 8; ++e) {
            float f = (float)b[e];
            vals[j][e] = f;
            mx = fmaxf(mx, f);
        }
    }
    sm[tid] = mx;
    __syncthreads();
    for (int off = 128; off > 0; off >>= 1) {
        if (tid < off) sm[tid] = fmaxf(sm[tid], sm[tid + off]);
        __syncthreads();
    }
    float M = sm[0];
    float s = (M - gmin) / 254.f;
    float inv = 254.f / (M - gmin);
    if (tid == 0) sh[row] = make_float2(s, 127.f * s + gmin);
    #pragma unroll
    for (int j = 0; j < 4; ++j) {
        char4 o0, o1;
        int q[8];
        #pragma unroll
        for (int e = 0; e < 8; ++e)
            q[e] = min(127, max(-127, __float2int_rn((vals[j][e] - gmin) * inv) - 127));
        o0.x = q[0]; o0.y = q[1]; o0.z = q[2]; o0.w = q[3];
        o1.x = q[4]; o1.y = q[5]; o1.z = q[6]; o1.w = q[7];
        int8_t* p = hq + (size_t)row * D_FF + j * 2048 + tid * 8;
        *(char4*)p = o0;
        *(char4*)(p + 4) = o1;
    }
}

// ===================================================================================
// 256x256 i8 MFMA GEMM, phase-interleaved counted-vmcnt pipeline (T1..T5).
//   C = A[M,K] * B[N,K]^T
//   512 threads = 8 waves (2M x 4N), per-wave output 128x64.
//   K consumed in halves of BK=64; LDS ring of 4 stages (A:16KiB + B:16KiB each)
//   staged 3 halves ahead via global_load_lds(16B). Steady-state boundary wait is
//   s_waitcnt vmcnt(8) (2 halves stay in flight across every barrier); drains to 0
//   only on the last two iterations. Raw s_barrier (+sched_barrier pins), never
//   __syncthreads() in the K-loop.
//   LDS layout per stage: row-major [256 rows][64 B], 16B chunk c of row r stored at
//   slot c ^ ((r>>1)&3)  -> frag reads (16 consecutive rows, fixed chunk) hit 8
//   distinct bank-quads, 2 lanes each = conflict-free (m136: 2-way is free).
// EPI==0 (fc1): h[m,n] = bf16( gelu( rs[m] * acc + bias[n] ) )
// EPI==1 (fc2): out[m,n] = f32( rs2[m].x * acc + rs2[m].y * colsum[n] + bias[n] )
// ===================================================================================
template<int EPI>
__global__ __launch_bounds__(512, 2) void gemm_i8_256(
    const int8_t* __restrict__ A,    // [M,K]
    const int8_t* __restrict__ B,    // [N,K]
    const float*  __restrict__ bias, // [N]
    const float*  __restrict__ rs,   // fc1: sx[M] ; fc2: (float2*)sh[M]
    const float*  __restrict__ colsum, // fc2 only: [N]
    void* __restrict__ Cout,
    int M, int N, int K)
{
    __shared__ int8_t As[4][16384];   // 4 ring stages x 256 rows x 64 B
    __shared__ int8_t Bs[4][16384];

    const int tid  = threadIdx.x;
    const int wave = tid >> 6;
    const int lane = tid & 63;
    const int quad = lane >> 4;
    const int l15  = lane & 15;
    const int wm   = (wave >> 2) * 128;   // 2 wave-rows of M
    const int wn   = (wave & 3) * 64;     // 4 wave-cols of N

    // T1: bijective XCD swizzle of the linear block id (both grids are %8==0)
    const int gx   = gridDim.x;
    const int nwg  = gx * gridDim.y;
    const int orig = blockIdx.y * gx + blockIdx.x;
    const int cpx  = nwg >> 3;
    const int swz  = (orig & 7) * cpx + (orig >> 3);
    const int m0   = (swz / gx) * 256;
    const int n0   = (swz % gx) * 256;

    i32x4 acc[8][4] = {};

    // ---- staging pointers: per K-half, A = 1024 chunks of 16B, 2 per thread ----
    const int8_t* gA[2]; const int8_t* gB[2];
    char* lA[2]; char* lB[2];
    #pragma unroll
    for (int it = 0; it < 2; ++it) {
        int slot = it * 512 + tid;           // [0,1024)
        int row  = slot >> 2;                // [0,256)
        int cg   = (slot & 3) ^ ((row >> 1) & 3);   // un-swizzled global chunk
        gA[it] = A + (size_t)(m0 + row) * K + cg * 16;
        gB[it] = B + (size_t)(n0 + row) * K + cg * 16;
        lA[it] = (char*)&As[0][0] + it * 8192 + wave * 1024;  // + lane*16 by HW
        lB[it] = (char*)&Bs[0][0] + it * 8192 + wave * 1024;
    }

    // ---- per-thread fragment LDS offsets (qm=0 rows; qm=1 adds 64 rows = +4096B,
    //      chunk swizzle term unchanged since (r+64)>>1 changes by 32 ≡ 0 mod 4) ----
    int aoff[4], boff[4];
    #pragma unroll
    for (int f = 0; f < 4; ++f) {
        int ra = wm + f * 16 + l15;
        aoff[f] = ra * 64 + ((quad ^ ((ra >> 1) & 3)) << 4);
        int rb = wn + f * 16 + l15;
        boff[f] = rb * 64 + ((quad ^ ((rb >> 1) & 3)) << 4);
    }

    const int NH = K >> 6;    // number of BK=64 halves (>= 32 here)

    // ---- prologue: stage halves 0,1,2 (12 loads); wait until half 0 landed ----
    #pragma unroll
    for (int h = 0; h < 3; ++h) {
        #pragma unroll
        for (int it = 0; it < 2; ++it) {
            GLOAD_LDS16(gA[it], lA[it] + h * 16384);
            GLOAD_LDS16(gB[it], lB[it] + h * 16384);
            gA[it] += 64; gB[it] += 64;
        }
    }
    asm volatile("s_waitcnt vmcnt(8)" ::: "memory");
    __builtin_amdgcn_s_barrier();
    __builtin_amdgcn_sched_barrier(0);

    for (int s = 0; s < NH; ++s) {
        const int8_t* Ap = &As[s & 3][0];
        const int8_t* Bp = &Bs[s & 3][0];
        const int stg = (s + 3) & 3;
        const bool stage = (s + 3) < NH;
        i32x4 af[4], bf[4];

        // ================= phase 0: quadrant qm=0 =================
        #pragma unroll
        for (int f = 0; f < 4; ++f) bf[f] = *(const i32x4*)(Bp + boff[f]);
        #pragma unroll
        for (int f = 0; f < 4; ++f) af[f] = *(const i32x4*)(Ap + aoff[f]);
        if (stage) {
            GLOAD_LDS16(gA[0], lA[0] + stg * 16384);
            GLOAD_LDS16(gB[0], lB[0] + stg * 16384);
            gA[0] += 64; gB[0] += 64;
        }
        __builtin_amdgcn_sched_barrier(0);
        __builtin_amdgcn_s_barrier();
        __builtin_amdgcn_sched_barrier(0);
        __builtin_amdgcn_s_setprio(1);
        #pragma unroll
        for (int mf = 0; mf < 4; ++mf)
            #pragma unroll
            for (int nf = 0; nf < 4; ++nf)
                acc[mf][nf] = __builtin_amdgcn_mfma_i32_16x16x64_i8(
                    af[mf], bf[nf], acc[mf][nf], 0, 0, 0);
        __builtin_amdgcn_s_setprio(0);
        __builtin_amdgcn_sched_barrier(0);
        __builtin_amdgcn_s_barrier();
        __builtin_amdgcn_sched_barrier(0);

        // ================= phase 1: quadrant qm=1 =================
        #pragma unroll
        for (int f = 0; f < 4; ++f) af[f] = *(const i32x4*)(Ap + 4096 + aoff[f]);
        if (stage) {
            GLOAD_LDS16(gA[1], lA[1] + stg * 16384);
            GLOAD_LDS16(gB[1], lB[1] + stg * 16384);
            gA[1] += 64; gB[1] += 64;
        }
        __builtin_amdgcn_sched_barrier(0);
        __builtin_amdgcn_s_barrier();
        __builtin_amdgcn_sched_barrier(0);
        __builtin_amdgcn_s_setprio(1);
        #pragma unroll
        for (int mf = 0; mf < 4; ++mf)
            #pragma unroll
            for (int nf = 0; nf < 4; ++nf)
                acc[4 + mf][nf] = __builtin_amdgcn_mfma_i32_16x16x64_i8(
                    af[mf], bf[nf], acc[4 + mf][nf], 0, 0, 0);
        __builtin_amdgcn_s_setprio(0);
        // ---- boundary: counted vmcnt — next half must be landed; keep the 2
        //      younger halves (8 loads) in flight. Drain only at the tail. ----
        if (s < NH - 3)       { asm volatile("s_waitcnt vmcnt(8)" ::: "memory"); }
        else if (s == NH - 3) { asm volatile("s_waitcnt vmcnt(4)" ::: "memory"); }
        else if (s == NH - 2) { asm volatile("s_waitcnt vmcnt(0)" ::: "memory"); }
        __builtin_amdgcn_sched_barrier(0);
        __builtin_amdgcn_s_barrier();
        __builtin_amdgcn_sched_barrier(0);
    }

    // ---- epilogue: C/D layout col = lane&15, row = quad*4 + r ----
    #pragma unroll
    for (int nf = 0; nf < 4; ++nf) {
        const int n = n0 + wn + nf * 16 + l15;
        const float bv = bias[n];
        const float cs = (EPI == 1) ? colsum[n] : 0.f;
        #pragma unroll
        for (int qm = 0; qm < 2; ++qm)
            #pragma unroll
            for (int mf = 0; mf < 4; ++mf)
                #pragma unroll
                for (int r = 0; r < 4; ++r) {
                    int m = m0 + wm + qm * 64 + mf * 16 + quad * 4 + r;
                    float a = (float)acc[qm * 4 + mf][nf][r];
                    if (EPI == 0) {
                        float v = rs[m] * a + bv;
                        v = 0.5f * v * (1.0f + erff(v * 0.70710678118654752f));
                        ((__bf16*)Cout)[(size_t)m * N + n] = (__bf16)v;
                    } else {
                        float2 so = ((const float2*)rs)[m];
                        ((float*)Cout)[(size_t)m * N + n] = so.x * a + so.y * cs + bv;
                    }
                }
    }
}

extern "C" void kernel_launch(void* const* d_in, const int* in_sizes, int n_in,
                              void* d_out, int out_size, void* d_ws, size_t ws_size,
                              hipStream_t stream) {
    const float* x  = (const float*)d_in[0];
    const float* w1 = (const float*)d_in[1];
    const float* b1 = (const float*)d_in[2];
    const float* w2 = (const float*)d_in[3];
    const float* b2 = (const float*)d_in[4];
    float* out = (float*)d_out;

    // workspace layout (bytes):
    //   0       : thr[2] float                  (pad to 256)
    //   256     : sx     float [16384]           64 KiB
    //   +64Ki   : sh     float2[16384]          128 KiB
    //   +128Ki  : colsum float [2048]             8 KiB (pad to 64 KiB)
    //   256Ki+256: xq    i8 [16384,2048]         32 MiB
    //   next    : w1q    i8 [ 8192,2048]         16 MiB
    //   next    : w2q    i8 [ 2048,8192]         16 MiB
    //   next    : hq     i8 [16384,8192]        128 MiB
    //   next    : h      bf16 [16384,8192]      256 MiB (absum partials alias h)
    char* ws = (char*)d_ws;
    float*  thr = (float*)ws;
    float*  sx  = (float*)(ws + 256);
    float2* sh  = (float2*)(ws + 256 + (64 << 10));
    float*  colsum = (float*)(ws + 256 + (192 << 10));
    int8_t* xq  = (int8_t*)(ws + 256 + (256 << 10));
    int8_t* w1q = xq  + (size_t)MTOK * D_MODEL;
    int8_t* w2q = w1q + (size_t)D_FF * D_MODEL;
    int8_t* hq  = w2q + (size_t)D_MODEL * D_FF;
    __bf16* h   = (__bf16*)(hq + (size_t)MTOK * D_FF);
    double* partials = (double*)h;   // 16 KiB, consumed before h is written

    absum_s1<<<dim3(1024, 2), 256, 0, stream>>>(w1, w2, partials);
    absum_s2<<<1, 256, 0, stream>>>(partials, thr);

    quantw1<<<NW / 1024, 256, 0, stream>>>(w1, thr, w1q);
    quantw2<<<D_MODEL, 256, 0, stream>>>(w2, thr, w2q, colsum);
    xquant<<<MTOK, 256, 0, stream>>>(x, xq, sx);

    dim3 g1(D_FF / 256, MTOK / 256);     // (32, 64)
    gemm_i8_256<0><<<g1, 512, 0, stream>>>(xq, w1q, b1, sx, nullptr, (void*)h,
                                           MTOK, D_FF, D_MODEL);

    hquant<<<MTOK, 256, 0, stream>>>(h, hq, sh);

    dim3 g2(D_MODEL / 256, MTOK / 256);  // (8, 64)
    gemm_i8_256<1><<<g2, 512, 0, stream>>>(hq, w2q, b2, (const float*)sh, colsum, (void*)out,
                                           MTOK, D_MODEL, D_FF);
}

// Round 2
// 1114.777 us; speedup vs baseline: 1.1399x; 1.1399x over previous
//
#include <hip/hip_runtime.h>
#include <hip/hip_bf16.h>
#include <math.h>
#include <stdint.h>

#define D_MODEL 2048
#define D_FF    8192
#define MTOK    16384   // 4 * 4096 tokens
#define NW      (D_FF * D_MODEL)   // elements per weight matrix

typedef int    i32x4  __attribute__((ext_vector_type(4)));
typedef __bf16 bf16x8 __attribute__((ext_vector_type(8)));

// width-16 async global->LDS (per-lane global addr, wave-uniform LDS base + lane*16)
#define GLOAD_LDS16(gp, lp)                                                   \
  __builtin_amdgcn_global_load_lds(                                           \
      (__attribute__((address_space(1))) void*)(gp),                          \
      (__attribute__((address_space(3))) void*)(lp), 16, 0, 0)

// ---------------- stage 1: deterministic double partial sums of |w| ----------------
__global__ void absum_s1(const float* __restrict__ w1, const float* __restrict__ w2,
                         double* __restrict__ partials) {
    const float* w = blockIdx.y ? w2 : w1;
    __shared__ double sm[256];
    int tid = blockIdx.x * 256 + threadIdx.x;
    double s = 0.0;
    for (int i = tid; i < NW / 4; i += 1024 * 256) {
        float4 v = ((const float4*)w)[i];
        s += (double)fabsf(v.x) + (double)fabsf(v.y) + (double)fabsf(v.z) + (double)fabsf(v.w);
    }
    sm[threadIdx.x] = s;
    __syncthreads();
    for (int off = 128; off > 0; off >>= 1) {
        if (threadIdx.x < off) sm[threadIdx.x] += sm[threadIdx.x + off];
        __syncthreads();
    }
    if (threadIdx.x == 0) partials[blockIdx.y * 1024 + blockIdx.x] = sm[0];
}

// ---------------- stage 2: 1024 partials -> float threshold 0.7*mean ----------------
__global__ void absum_s2(const double* __restrict__ partials, float* __restrict__ thr) {
    __shared__ double sm[256];
    for (int wsel = 0; wsel < 2; ++wsel) {
        const double* p = partials + wsel * 1024;
        double s = p[threadIdx.x] + p[threadIdx.x + 256] + p[threadIdx.x + 512] + p[threadIdx.x + 768];
        sm[threadIdx.x] = s;
        __syncthreads();
        for (int off = 128; off > 0; off >>= 1) {
            if (threadIdx.x < off) sm[threadIdx.x] += sm[threadIdx.x + off];
            __syncthreads();
        }
        if (threadIdx.x == 0) thr[wsel] = (float)(0.7 * (sm[0] / (double)NW));
        __syncthreads();
    }
}

// ---------------- w1 -> ternary i8, elementwise ----------------
__global__ void quantw1(const float* __restrict__ w, const float* __restrict__ thr,
                        int8_t* __restrict__ q) {
    float t = thr[0];
    int i = (blockIdx.x * 256 + threadIdx.x) * 4;
    float4 v = *(const float4*)(w + i);
    char4 o;
    o.x = (fabsf(v.x) >= t) ? (v.x > 0.f ? 1 : -1) : 0;
    o.y = (fabsf(v.y) >= t) ? (v.y > 0.f ? 1 : -1) : 0;
    o.z = (fabsf(v.z) >= t) ? (v.z > 0.f ? 1 : -1) : 0;
    o.w = (fabsf(v.w) >= t) ? (v.w > 0.f ? 1 : -1) : 0;
    *(char4*)(q + i) = o;
}

// ---------------- w2 -> ternary i8, one block per row, + row sums (colsum) ---------
__global__ void quantw2(const float* __restrict__ w, const float* __restrict__ thr,
                        int8_t* __restrict__ q, float* __restrict__ colsum) {
    __shared__ int sm[256];
    float t = thr[1];
    const int row = blockIdx.x;
    const int tid = threadIdx.x;
    int isum = 0;
    #pragma unroll
    for (int j = 0; j < 8; ++j) {
        int idx = row * D_FF + j * 1024 + tid * 4;
        float4 v = *(const float4*)(w + idx);
        char4 o;
        o.x = (fabsf(v.x) >= t) ? (v.x > 0.f ? 1 : -1) : 0;
        o.y = (fabsf(v.y) >= t) ? (v.y > 0.f ? 1 : -1) : 0;
        o.z = (fabsf(v.z) >= t) ? (v.z > 0.f ? 1 : -1) : 0;
        o.w = (fabsf(v.w) >= t) ? (v.w > 0.f ? 1 : -1) : 0;
        isum += o.x + o.y + o.z + o.w;
        *(char4*)(q + idx) = o;
    }
    sm[tid] = isum;
    __syncthreads();
    for (int off = 128; off > 0; off >>= 1) {
        if (tid < off) sm[tid] += sm[tid + off];
        __syncthreads();
    }
    if (tid == 0) colsum[row] = (float)sm[0];
}

// ---------------- x -> per-row symmetric i8, one block per token row ----------------
__global__ void xquant(const float* __restrict__ x, int8_t* __restrict__ xq,
                       float* __restrict__ sx) {
    __shared__ float sm[256];
    const int row = blockIdx.x;
    const int tid = threadIdx.x;
    float4 v[2];
    float mx = 0.f;
    #pragma unroll
    for (int j = 0; j < 2; ++j) {
        v[j] = *(const float4*)(x + (size_t)row * D_MODEL + j * 1024 + tid * 4);
        mx = fmaxf(mx, fmaxf(fmaxf(fabsf(v[j].x), fabsf(v[j].y)),
                             fmaxf(fabsf(v[j].z), fabsf(v[j].w))));
    }
    sm[tid] = mx;
    __syncthreads();
    for (int off = 128; off > 0; off >>= 1) {
        if (tid < off) sm[tid] = fmaxf(sm[tid], sm[tid + off]);
        __syncthreads();
    }
    float m = sm[0];
    float inv = (m > 0.f) ? 127.f / m : 0.f;
    if (tid == 0) sx[row] = (m > 0.f) ? m / 127.f : 0.f;
    #pragma unroll
    for (int j = 0; j < 2; ++j) {
        char4 o;
        o.x = (int8_t)min(127, max(-127, __float2int_rn(v[j].x * inv)));
        o.y = (int8_t)min(127, max(-127, __float2int_rn(v[j].y * inv)));
        o.z = (int8_t)min(127, max(-127, __float2int_rn(v[j].z * inv)));
        o.w = (int8_t)min(127, max(-127, __float2int_rn(v[j].w * inv)));
        *(char4*)(xq + (size_t)row * D_MODEL + j * 1024 + tid * 4) = o;
    }
}

// ---------------- gelu(h) bf16 -> per-row ASYMMETRIC i8 (zero-point via colsum) -----
__global__ void hquant(const __bf16* __restrict__ h, int8_t* __restrict__ hq,
                       float2* __restrict__ sh) {
    __shared__ float sm[256];
    const int row = blockIdx.x;
    const int tid = threadIdx.x;
    const float gmin = -0.17f;
    float vals[4][8];
    float mx = -1e30f;
    #pragma unroll
    for (int j = 0; j < 4; ++j) {
        bf16x8 b = *(const bf16x8*)(h + (size_t)row * D_FF + j * 2048 + tid * 8);
        #pragma unroll
        for (int e = 0; e < 8; ++e) {
            float f = (float)b[e];
            vals[j][e] = f;
            mx = fmaxf(mx, f);
        }
    }
    sm[tid] = mx;
    __syncthreads();
    for (int off = 128; off > 0; off >>= 1) {
        if (tid < off) sm[tid] = fmaxf(sm[tid], sm[tid + off]);
        __syncthreads();
    }
    float M = sm[0];
    float s = (M - gmin) / 254.f;
    float inv = 254.f / (M - gmin);
    if (tid == 0) sh[row] = make_float2(s, 127.f * s + gmin);
    #pragma unroll
    for (int j = 0; j < 4; ++j) {
        char4 o0, o1;
        int q[8];
        #pragma unroll
        for (int e = 0; e < 8; ++e)
            q[e] = min(127, max(-127, __float2int_rn((vals[j][e] - gmin) * inv) - 127));
        o0.x = q[0]; o0.y = q[1]; o0.z = q[2]; o0.w = q[3];
        o1.x = q[4]; o1.y = q[5]; o1.z = q[6]; o1.w = q[7];
        int8_t* p = hq + (size_t)row * D_FF + j * 2048 + tid * 8;
        *(char4*)p = o0;
        *(char4*)(p + 4) = o1;
    }
}

// ===================================================================================
// 256x128 i8 MFMA GEMM, 2 blocks/CU (latency-bound fix: TLP over lockstep).
//   C = A[M,K] * B[N,K]^T ; 512 threads = 8 waves (4M x 2N), per-wave 64x64.
//   LDS ring-3 of 24 KiB stages (A 256x64 = 16K, B 128x64 = 8K) = 72 KiB total
//   -> 2 blocks/CU by LDS; __launch_bounds__(512,4) caps regs at 128/wave
//   (acc = 64 AGPR) -> 2 blocks/CU by registers too. When one block waits at
//   its barrier/vmcnt the other block's waves feed the matrix pipe.
//   Per K-half (BK=64): 3 gloads/thread (stage s+2), 8 ds_read_b128, 16 MFMA,
//   counted s_waitcnt vmcnt(3), ONE s_barrier. (Stage s was published by the
//   vmcnt(3)+barrier at the end of iteration s-1, so reads can issue at iteration
//   start; the single closing barrier both publishes stage s+1 and protects the
//   stage being overwritten.)
//   16B chunk c of row r stored at slot c^((r>>1)&3): frag reads are 2-way = free.
// EPI==0 (fc1): h[m,n] = bf16( gelu( rs[m] * acc + bias[n] ) ), block map = T1 swz.
// EPI==1 (fc2): out = rs2[m].x * acc + rs2[m].y * colsum[n] + bias[n]; block map
//   partitions M across XCDs in 4-row supertiles (hq fetched ~once, not 8x).
// ===================================================================================
template<int EPI>
__global__ __launch_bounds__(512, 4) void gemm_i8_bt(
    const int8_t* __restrict__ A,    // [M,K]
    const int8_t* __restrict__ B,    // [N,K]
    const float*  __restrict__ bias, // [N]
    const float*  __restrict__ rs,   // fc1: sx[M] ; fc2: (float2*)sh[M]
    const float*  __restrict__ colsum, // fc2 only: [N]
    void* __restrict__ Cout,
    int M, int N, int K)
{
    __shared__ int8_t Sh[3 * 24576];   // ring-3: per stage A[256][64] + B[128][64]

    const int tid  = threadIdx.x;
    const int wave = tid >> 6;
    const int lane = tid & 63;
    const int quad = lane >> 4;
    const int l15  = lane & 15;
    const int wm   = (wave >> 1) * 64;    // 4 wave-rows of M
    const int wn   = (wave & 1) * 64;     // 2 wave-cols of N

    // ---- block -> tile map ----
    const int gx   = gridDim.x;
    const int nwg  = gx * gridDim.y;
    const int orig = blockIdx.y * gx + blockIdx.x;
    int by, bx;
    if (EPI == 0) {
        // fc1 (gx=64): T1 bijective XCD swizzle on the linear id
        const int swz = (orig & 7) * (nwg >> 3) + (orig >> 3);
        by = swz >> 6;               // / 64
        bx = swz & 63;
    } else {
        // fc2 (gx=16): XCD x owns by in [x*8, x*8+8), 4-row supertiles, bx-major
        // inside a supertile with 4-row bursts (B panel reused 4x back-to-back).
        const int xcd = orig & 7;
        const int l   = orig >> 3;   // [0, 128)
        const int st  = l >> 6;      // supertile 0/1  (gx*4 = 64)
        const int r   = l & 63;
        by = xcd * 8 + st * 4 + (r & 3);
        bx = r >> 2;
    }
    const int m0 = by << 8;   // *256
    const int n0 = bx << 7;   // *128

    i32x4 acc[4][4] = {};

    // ---- staging: per K-half, A = 1024 chunks (2/thread), B = 512 chunks (1/thread)
    const int row0 = tid >> 2;
    const int cg0  = (tid & 3) ^ ((row0 >> 1) & 3);   // same for row0 and row0+128
    const int8_t* gA0 = A + (size_t)(m0 + row0) * K + cg0 * 16;
    const int8_t* gA1 = gA0 + (size_t)128 * K;
    const int8_t* gB0 = B + (size_t)(n0 + row0) * K + cg0 * 16;
    char* const ldsb = (char*)Sh;
    char* const dA0  = ldsb + wave * 1024;            // + lane*16 by HW
    char* const dA1  = ldsb + 8192  + wave * 1024;
    char* const dB0  = ldsb + 16384 + wave * 1024;

    // ---- per-thread fragment LDS offsets (within a stage) ----
    int aoff[4], boff[4];
    #pragma unroll
    for (int f = 0; f < 4; ++f) {
        int ra = wm + f * 16 + l15;
        aoff[f] = ra * 64 + ((quad ^ ((ra >> 1) & 3)) << 4);
        int rb = wn + f * 16 + l15;
        boff[f] = 16384 + rb * 64 + ((quad ^ ((rb >> 1) & 3)) << 4);
    }

    const int NH = K >> 6;   // BK=64 halves (fc1: 32, fc2: 128)
    const int STG = 24576;

    // ---- prologue: stage halves 0,1 (6 loads/thread); wait half 0 ----
    #pragma unroll
    for (int h = 0; h < 2; ++h) {
        GLOAD_LDS16(gA0, dA0 + h * STG);
        GLOAD_LDS16(gA1, dA1 + h * STG);
        GLOAD_LDS16(gB0, dB0 + h * STG);
        gA0 += 64; gA1 += 64; gB0 += 64;
    }
    asm volatile("s_waitcnt vmcnt(3)" ::: "memory");
    __builtin_amdgcn_s_barrier();
    __builtin_amdgcn_sched_barrier(0);

    int roff = 0;             // stage being read   (s % 3) * STG
    int soff = 2 * STG;       // stage being filled ((s+2) % 3) * STG

    for (int s = 0; s < NH; ++s) {
        // issue next-next stage loads first (earliest HBM start)
        if (s + 2 < NH) {
            GLOAD_LDS16(gA0, ldsb + soff + (dA0 - ldsb));
            GLOAD_LDS16(gA1, ldsb + soff + (dA1 - ldsb));
            GLOAD_LDS16(gB0, ldsb + soff + (dB0 - ldsb));
            gA0 += 64; gA1 += 64; gB0 += 64;
        }
        i32x4 bfr[4];
        #pragma unroll
        for (int f = 0; f < 4; ++f) bfr[f] = *(const i32x4*)(ldsb + roff + boff[f]);
        __builtin_amdgcn_s_setprio(1);
        #pragma unroll
        for (int mf = 0; mf < 4; ++mf) {
            i32x4 af = *(const i32x4*)(ldsb + roff + aoff[mf]);
            #pragma unroll
            for (int nf = 0; nf < 4; ++nf)
                acc[mf][nf] = __builtin_amdgcn_mfma_i32_16x16x64_i8(
                    af, bfr[nf], acc[mf][nf], 0, 0, 0);
        }
        __builtin_amdgcn_s_setprio(0);
        // counted boundary: stage s+1 must be landed; keep stage s+2 in flight
        if (s < NH - 2)       { asm volatile("s_waitcnt vmcnt(3)" ::: "memory"); }
        else if (s == NH - 2) { asm volatile("s_waitcnt vmcnt(0)" ::: "memory"); }
        __builtin_amdgcn_sched_barrier(0);
        __builtin_amdgcn_s_barrier();
        __builtin_amdgcn_sched_barrier(0);
        roff = (roff == 2 * STG) ? 0 : roff + STG;
        soff = (soff == 2 * STG) ? 0 : soff + STG;
    }

    // ---- epilogue: C/D layout col = lane&15, row = quad*4 + r ----
    #pragma unroll
    for (int nf = 0; nf < 4; ++nf) {
        const int n = n0 + wn + nf * 16 + l15;
        const float bv = bias[n];
        const float cs = (EPI == 1) ? colsum[n] : 0.f;
        #pragma unroll
        for (int mf = 0; mf < 4; ++mf)
            #pragma unroll
            for (int r = 0; r < 4; ++r) {
                int m = m0 + wm + mf * 16 + quad * 4 + r;
                float a = (float)acc[mf][nf][r];
                if (EPI == 0) {
                    float v = rs[m] * a + bv;
                    v = 0.5f * v * (1.0f + erff(v * 0.70710678118654752f));
                    ((__bf16*)Cout)[(size_t)m * N + n] = (__bf16)v;
                } else {
                    float2 so = ((const float2*)rs)[m];
                    ((float*)Cout)[(size_t)m * N + n] = so.x * a + so.y * cs + bv;
                }
            }
    }
}

extern "C" void kernel_launch(void* const* d_in, const int* in_sizes, int n_in,
                              void* d_out, int out_size, void* d_ws, size_t ws_size,
                              hipStream_t stream) {
    const float* x  = (const float*)d_in[0];
    const float* w1 = (const float*)d_in[1];
    const float* b1 = (const float*)d_in[2];
    const float* w2 = (const float*)d_in[3];
    const float* b2 = (const float*)d_in[4];
    float* out = (float*)d_out;

    char* ws = (char*)d_ws;
    float*  thr = (float*)ws;
    float*  sx  = (float*)(ws + 256);
    float2* sh  = (float2*)(ws + 256 + (64 << 10));
    float*  colsum = (float*)(ws + 256 + (192 << 10));
    int8_t* xq  = (int8_t*)(ws + 256 + (256 << 10));
    int8_t* w1q = xq  + (size_t)MTOK * D_MODEL;
    int8_t* w2q = w1q + (size_t)D_FF * D_MODEL;
    int8_t* hq  = w2q + (size_t)D_MODEL * D_FF;
    __bf16* h   = (__bf16*)(hq + (size_t)MTOK * D_FF);
    double* partials = (double*)h;   // 16 KiB, consumed before h is written

    absum_s1<<<dim3(1024, 2), 256, 0, stream>>>(w1, w2, partials);
    absum_s2<<<1, 256, 0, stream>>>(partials, thr);

    quantw1<<<NW / 1024, 256, 0, stream>>>(w1, thr, w1q);
    quantw2<<<D_MODEL, 256, 0, stream>>>(w2, thr, w2q, colsum);
    xquant<<<MTOK, 256, 0, stream>>>(x, xq, sx);

    dim3 g1(D_FF / 128, MTOK / 256);     // (64, 64)
    gemm_i8_bt<0><<<g1, 512, 0, stream>>>(xq, w1q, b1, sx, nullptr, (void*)h,
                                          MTOK, D_FF, D_MODEL);

    hquant<<<MTOK, 256, 0, stream>>>(h, hq, sh);

    dim3 g2(D_MODEL / 128, MTOK / 256);  // (16, 64)
    gemm_i8_bt<1><<<g2, 512, 0, stream>>>(hq, w2q, b2, (const float*)sh, colsum, (void*)out,
                                          MTOK, D_MODEL, D_FF);
}